// Round 8
// baseline (814.697 us; speedup 1.0000x reference)
//
#include <hip/hip_runtime.h>

#define MUL0 64
#define MUL1 32
#define DFEAT 160

__device__ __constant__ float kINV3 = 0.57735026918962576451f;  // 1/sqrt(3)
__device__ __constant__ float kINV6 = 0.40824829046386301637f;  // 1/sqrt(6)
__device__ __constant__ float kC0   = 0.10206207261596575f;     // 1/sqrt(96)
__device__ __constant__ float kC1   = 0.15309310892394863f;     // sqrt(3/128)
__device__ __constant__ float kLS   = 0.125f;                   // 1/sqrt(64)
__device__ __constant__ float kLV   = 0.17677669529663687f;     // 1/sqrt(32)

#define WAVE_SYNC() do { \
    asm volatile("s_waitcnt lgkmcnt(0)" ::: "memory"); \
    __builtin_amdgcn_sched_barrier(0); \
} while (0)

// ---------- CSR build ----------
__global__ void hist_kernel(const int* __restrict__ dst, int* __restrict__ deg, int E) {
    for (int e = blockIdx.x * blockDim.x + threadIdx.x; e < E; e += gridDim.x * blockDim.x)
        atomicAdd(&deg[dst[e]], 1);
}

// single block, 1024 threads: exclusive scan of deg -> rowptr; deg becomes cursor copy
__global__ __launch_bounds__(1024) void scan_kernel(int* __restrict__ deg,
                                                    int* __restrict__ rowptr, int N) {
    __shared__ int sums[1024];
    const int t = threadIdx.x;
    const int per = (N + 1023) / 1024;
    const int base = t * per;
    int s = 0;
    for (int i = 0; i < per; ++i) {
        const int idx = base + i;
        if (idx < N) s += deg[idx];
    }
    sums[t] = s;
    __syncthreads();
    // Hillis-Steele inclusive scan
    for (int off = 1; off < 1024; off <<= 1) {
        int v = (t >= off) ? sums[t - off] : 0;
        __syncthreads();
        sums[t] += v;
        __syncthreads();
    }
    int run = (t == 0) ? 0 : sums[t - 1];
    for (int i = 0; i < per; ++i) {
        const int idx = base + i;
        if (idx < N) {
            const int d = deg[idx];
            rowptr[idx] = run;
            deg[idx] = run;   // cursor
            run += d;
        }
    }
    if (t == 0) rowptr[N] = sums[1023];
}

__global__ void scatter_kernel(const int* __restrict__ dst, int* __restrict__ cursor,
                               int* __restrict__ eids, int E) {
    for (int e = blockIdx.x * blockDim.x + threadIdx.x; e < E; e += gridDim.x * blockDim.x) {
        const int pos = atomicAdd(&cursor[dst[e]], 1);
        eids[pos] = e;
    }
}

// ---------- fused aggregation + node mix ----------
// One wave per node. Edge loop accumulates the 480-dim reduced state in regs:
//   A1=Σe0·ss(64)  A3i=Σe1i·ss(3×64)  A2=Σv·e1(32)  A4i=Σe0·vi(3×32)  A5i=Σcrossi(3×32)
// Then per-node GEMVs: m_s=C0(A1@W1+INV3·A2@W2); m_v[:,i]=C1(INV3(A3i@W3+A4i@W4)+INV6·A5i@W5)
// Then h=[m_s@Ws·LS ; (m_v@Wv)·LV]; out = x + relu(h).
__global__ __launch_bounds__(256) void node_fused_kernel(
    const float* __restrict__ x, const float* __restrict__ sh,
    const int* __restrict__ src, const int* __restrict__ eids,
    const int* __restrict__ rowptr,
    const float* __restrict__ W1, const float* __restrict__ W2,
    const float* __restrict__ W3, const float* __restrict__ W4,
    const float* __restrict__ W5, const float* __restrict__ Ws,
    const float* __restrict__ Wv,
    float* __restrict__ out, int N)
{
    __shared__ float sW1[4096];
    __shared__ float sW2[2048];
    __shared__ float sW3[2048];
    __shared__ float sW4[1024];
    __shared__ float sW5[1024];
    __shared__ float sWs[4096];
    __shared__ float sWv[1024];
    __shared__ float sSt[4][512];
    __shared__ float sM[4][160];

    const int tid = threadIdx.x;
    for (int i = tid; i < 4096; i += 256) sW1[i] = W1[i];
    for (int i = tid; i < 2048; i += 256) sW2[i] = W2[i];
    for (int i = tid; i < 2048; i += 256) sW3[i] = W3[i];
    for (int i = tid; i < 1024; i += 256) sW4[i] = W4[i];
    for (int i = tid; i < 1024; i += 256) sW5[i] = W5[i];
    for (int i = tid; i < 4096; i += 256) sWs[i] = Ws[i];
    for (int i = tid; i < 1024; i += 256) sWv[i] = Wv[i];
    __syncthreads();

    const int lane = tid & 63;
    const int wid  = tid >> 6;
    const bool lo  = (lane < 32);
    const int  u   = lo ? lane : (lane - 32);
    const int  w   = lane & 31;
    const int  iv  = lane >> 5;       // 0 or 1
    float* st = sSt[wid];
    float* sm = sM[wid];

    for (int n = blockIdx.x * 4 + wid; n < N; n += gridDim.x * 4) {
        const int beg = rowptr[n];
        const int end = rowptr[n + 1];

        float r0 = 0.f, r1 = 0.f, r2 = 0.f, r3 = 0.f;
        float r4 = 0.f, r5 = 0.f, r6 = 0.f, r7 = 0.f;

        int e = (beg < end) ? eids[beg] : 0;
        int s = (beg < end) ? src[e] : 0;
        for (int idx = beg; idx < end; ++idx) {
            const float4 sh4 = ((const float4*)sh)[e];
            const float* xr = x + (size_t)s * DFEAT;
            // prefetch next edge's indices (hides the eids->src->x chase)
            int en = 0, sn = 0;
            if (idx + 1 < end) { en = eids[idx + 1]; sn = src[en]; }
            const float e0 = sh4.x, e1x = sh4.y, e1y = sh4.z, e1z = sh4.w;
            const float xs = xr[lane];
            const float va = xr[64 + 3 * u];
            const float vb = xr[65 + 3 * u];
            const float vc = xr[66 + 3 * u];
            r0 += e0  * xs;
            r1 += e1x * xs;
            r2 += e1y * xs;
            r3 += e1z * xs;
            r4 += lo ? (va * e1x + vb * e1y + vc * e1z) : (e0 * va);
            r5 += e0 * (lo ? vb : vc);
            r6 += lo ? (vb * e1z - vc * e1y) : (vc * e1x - va * e1z);
            r7 += lo ? (va * e1y - vb * e1x) : 0.f;
            e = en; s = sn;
        }

        // store reduced state (scales folded): layout
        // [0..63]=A1, [64..127]=INV3·A3x, [128..191]=INV3·A3y, [192..255]=INV3·A3z,
        // [256..287]=INV3·A2, [288..319]=INV3·A4x, [320..351]=INV3·A4y, [352..383]=INV3·A4z,
        // [384..415]=INV6·A5x, [416..447]=INV6·A5y, [448..479]=INV6·A5z
        st[lane]       = r0;
        st[64 + lane]  = kINV3 * r1;
        st[128 + lane] = kINV3 * r2;
        st[192 + lane] = kINV3 * r3;
        st[256 + lane] = kINV3 * r4;
        st[320 + lane] = kINV3 * r5;
        st[384 + lane] = kINV6 * r6;
        if (lo) st[448 + lane] = kINV6 * r7;
        WAVE_SYNC();

        // ---- GEMV A: m_s[lane]
        {
            float a = 0.f;
            #pragma unroll 8
            for (int k = 0; k < 64; ++k) a += st[k] * sW1[k * 64 + lane];
            #pragma unroll 8
            for (int k = 0; k < 32; ++k) a += st[256 + k] * sW2[k * 64 + lane];
            sm[lane] = kC0 * a;
        }
        // ---- GEMV B: m_v[w, iv] for iv=0,1 (all lanes) and iv=2 (lanes<32)
        {
            float b = 0.f;
            #pragma unroll 8
            for (int k = 0; k < 64; ++k) b += st[64 + 64 * iv + k] * sW3[k * 32 + w];
            #pragma unroll 8
            for (int k = 0; k < 32; ++k) b += st[288 + 32 * iv + k] * sW4[k * 32 + w];
            #pragma unroll 8
            for (int k = 0; k < 32; ++k) b += st[384 + 32 * iv + k] * sW5[k * 32 + w];
            sm[64 + 3 * w + iv] = kC1 * b;
        }
        if (lo) {
            float c = 0.f;
            #pragma unroll 8
            for (int k = 0; k < 64; ++k) c += st[192 + k] * sW3[k * 32 + lane];
            #pragma unroll 8
            for (int k = 0; k < 32; ++k) c += st[352 + k] * sW4[k * 32 + lane];
            #pragma unroll 8
            for (int k = 0; k < 32; ++k) c += st[448 + k] * sW5[k * 32 + lane];
            sm[64 + 3 * lane + 2] = kC1 * c;
        }
        WAVE_SYNC();

        // ---- final mix + residual ReLU
        const size_t o = (size_t)n * DFEAT;
        {
            float a = 0.f;
            #pragma unroll 8
            for (int k = 0; k < 64; ++k) a += sm[k] * sWs[k * 64 + lane];
            out[o + lane] = x[o + lane] + fmaxf(kLS * a, 0.f);
        }
        {
            float b = 0.f;
            #pragma unroll 8
            for (int k = 0; k < 32; ++k) b += sm[64 + 3 * k + iv] * sWv[k * 32 + w];
            out[o + 64 + 3 * w + iv] = x[o + 64 + 3 * w + iv] + fmaxf(kLV * b, 0.f);
        }
        if (lo) {
            float c = 0.f;
            #pragma unroll 8
            for (int k = 0; k < 32; ++k) c += sm[64 + 3 * k + 2] * sWv[k * 32 + lane];
            out[o + 64 + 3 * lane + 2] = x[o + 64 + 3 * lane + 2] + fmaxf(kLV * c, 0.f);
        }
        WAVE_SYNC();  // st/sm reads done before next node overwrites
    }
}

extern "C" void kernel_launch(void* const* d_in, const int* in_sizes, int n_in,
                              void* d_out, int out_size, void* d_ws, size_t ws_size,
                              hipStream_t stream) {
    const float* x  = (const float*)d_in[0];
    const float* sh = (const float*)d_in[1];
    const float* W1 = (const float*)d_in[2];
    const float* W2 = (const float*)d_in[3];
    const float* W3 = (const float*)d_in[4];
    const float* W4 = (const float*)d_in[5];
    const float* W5 = (const float*)d_in[6];
    const float* Ws = (const float*)d_in[7];
    const float* Wv = (const float*)d_in[8];
    const int*   ei = (const int*)d_in[9];

    const int E = in_sizes[9] / 2;
    const int N = in_sizes[0] / DFEAT;
    const int* src = ei;
    const int* dst = ei + E;

    int* deg    = (int*)d_ws;        // N ints (cursor after scan)
    int* rowptr = deg + N;           // N+1 ints
    int* eids   = rowptr + N + 1;    // E ints

    (void)hipMemsetAsync(deg, 0, (size_t)N * sizeof(int), stream);
    hist_kernel<<<2048, 256, 0, stream>>>(dst, deg, E);
    scan_kernel<<<1, 1024, 0, stream>>>(deg, rowptr, N);
    scatter_kernel<<<2048, 256, 0, stream>>>(dst, deg, eids, E);
    node_fused_kernel<<<2048, 256, 0, stream>>>(x, sh, src, eids, rowptr,
                                                W1, W2, W3, W4, W5, Ws, Wv,
                                                (float*)d_out, N);
}

// Round 9
// 394.546 us; speedup vs baseline: 2.0649x; 2.0649x over previous
//
#include <hip/hip_runtime.h>

#define DFEAT 160

__device__ __constant__ float kINV3 = 0.57735026918962576451f;  // 1/sqrt(3)
__device__ __constant__ float kINV6 = 0.40824829046386301637f;  // 1/sqrt(6)
__device__ __constant__ float kC0   = 0.10206207261596575f;     // 1/sqrt(96)
__device__ __constant__ float kC1   = 0.15309310892394863f;     // sqrt(3/128)
__device__ __constant__ float kLS   = 0.125f;                   // 1/sqrt(64)
__device__ __constant__ float kLV   = 0.17677669529663687f;     // 1/sqrt(32)

#define WAVE_SYNC() do { \
    asm volatile("s_waitcnt lgkmcnt(0)" ::: "memory"); \
    __builtin_amdgcn_sched_barrier(0); \
} while (0)

// ---------- CSR build ----------
__global__ void hist_kernel(const int* __restrict__ dst, int* __restrict__ deg, int E) {
    for (int e = blockIdx.x * blockDim.x + threadIdx.x; e < E; e += gridDim.x * blockDim.x)
        atomicAdd(&deg[dst[e]], 1);
}

__global__ __launch_bounds__(256) void blocksum_kernel(const int* __restrict__ deg,
                                                       int* __restrict__ bsum, int N) {
    __shared__ int red[256];
    const int b = blockIdx.x, t = threadIdx.x;
    const int base = b * 1024;
    int s = 0;
    for (int i = t; i < 1024; i += 256) {
        const int idx = base + i;
        if (idx < N) s += deg[idx];
    }
    red[t] = s;
    __syncthreads();
    for (int off = 128; off > 0; off >>= 1) {
        if (t < off) red[t] += red[t + off];
        __syncthreads();
    }
    if (t == 0) bsum[b] = red[0];
}

__global__ void scanb_kernel(int* __restrict__ bsum, int nb, int* __restrict__ rowptrN) {
    if (threadIdx.x == 0 && blockIdx.x == 0) {
        int run = 0;
        for (int i = 0; i < nb; ++i) { const int v = bsum[i]; bsum[i] = run; run += v; }
        *rowptrN = run;  // == E
    }
}

__global__ __launch_bounds__(256) void scanfinal_kernel(const int* __restrict__ deg,
                                                        const int* __restrict__ bsum,
                                                        int* __restrict__ rowptr,
                                                        int* __restrict__ cursor, int N) {
    __shared__ int ts[256];
    const int b = blockIdx.x, t = threadIdx.x;
    const int i0 = b * 1024 + t * 4;
    const int d0 = (i0 + 0 < N) ? deg[i0 + 0] : 0;
    const int d1 = (i0 + 1 < N) ? deg[i0 + 1] : 0;
    const int d2 = (i0 + 2 < N) ? deg[i0 + 2] : 0;
    const int d3 = (i0 + 3 < N) ? deg[i0 + 3] : 0;
    ts[t] = d0 + d1 + d2 + d3;
    __syncthreads();
    for (int off = 1; off < 256; off <<= 1) {
        const int v = (t >= off) ? ts[t - off] : 0;
        __syncthreads();
        ts[t] += v;
        __syncthreads();
    }
    int ex = bsum[b] + ((t == 0) ? 0 : ts[t - 1]);
    if (i0 + 0 < N) { rowptr[i0 + 0] = ex; cursor[i0 + 0] = ex; ex += d0; }
    if (i0 + 1 < N) { rowptr[i0 + 1] = ex; cursor[i0 + 1] = ex; ex += d1; }
    if (i0 + 2 < N) { rowptr[i0 + 2] = ex; cursor[i0 + 2] = ex; ex += d2; }
    if (i0 + 3 < N) { rowptr[i0 + 3] = ex; cursor[i0 + 3] = ex; ex += d3; }
}

__global__ void scatter_kernel(const int* __restrict__ dst, int* __restrict__ cursor,
                               int* __restrict__ eids, int E) {
    for (int e = blockIdx.x * blockDim.x + threadIdx.x; e < E; e += gridDim.x * blockDim.x) {
        const int pos = atomicAdd(&cursor[dst[e]], 1);
        eids[pos] = e;
    }
}

// ---------- weight fusion: Wf1=W1@Ws, Wf2=W2@Ws, Wf3=W3@Wv, Wf4=W4@Wv, Wf5=W5@Wv
// wf layout (floats): Wf1[64][64]@0, Wf2[32][64]@4096, Wf3[64][32]@6144,
//                     Wf4[32][32]@8192, Wf5[32][32]@9216  (10240 total)
__global__ __launch_bounds__(256) void fuse_kernel(
    const float* __restrict__ W1, const float* __restrict__ W2,
    const float* __restrict__ W3, const float* __restrict__ W4,
    const float* __restrict__ W5, const float* __restrict__ Ws,
    const float* __restrict__ Wv, float* __restrict__ wf)
{
    __shared__ float sWs[4096];
    __shared__ float sWv[1024];
    const int t = threadIdx.x;
    for (int i = t; i < 4096; i += 256) sWs[i] = Ws[i];
    for (int i = t; i < 1024; i += 256) sWv[i] = Wv[i];
    __syncthreads();
    for (int o = blockIdx.x * 256 + t; o < 10240; o += gridDim.x * 256) {
        float acc = 0.f;
        if (o < 4096) {
            const int k = o >> 6, j = o & 63;
            for (int m = 0; m < 64; ++m) acc += W1[k * 64 + m] * sWs[m * 64 + j];
        } else if (o < 6144) {
            const int i = o - 4096; const int k = i >> 6, j = i & 63;
            for (int m = 0; m < 64; ++m) acc += W2[k * 64 + m] * sWs[m * 64 + j];
        } else if (o < 8192) {
            const int i = o - 6144; const int k = i >> 5, j = i & 31;
            for (int m = 0; m < 32; ++m) acc += W3[k * 32 + m] * sWv[m * 32 + j];
        } else if (o < 9216) {
            const int i = o - 8192; const int k = i >> 5, j = i & 31;
            for (int m = 0; m < 32; ++m) acc += W4[k * 32 + m] * sWv[m * 32 + j];
        } else {
            const int i = o - 9216; const int k = i >> 5, j = i & 31;
            for (int m = 0; m < 32; ++m) acc += W5[k * 32 + m] * sWv[m * 32 + j];
        }
        wf[o] = acc;
    }
}

// ---------- fused aggregation + composed node transform ----------
// One wave per node, 8 waves/block (512 thr). Edge loop -> 480-dim reduced state
// in regs; then h = state @ fused-weights; out = x + relu(h).
__global__ __launch_bounds__(512, 4) void node_fused_kernel(
    const float* __restrict__ x, const float* __restrict__ sh,
    const int* __restrict__ src, const int* __restrict__ eids,
    const int* __restrict__ rowptr, const float* __restrict__ wf,
    float* __restrict__ out, int N)
{
    __shared__ float sWf[10240];
    __shared__ float sSt[8][480];

    const int tid = threadIdx.x;
    for (int i = tid; i < 10240; i += 512) sWf[i] = wf[i];
    __syncthreads();

    const float* sWf1 = sWf;
    const float* sWf2 = sWf + 4096;
    const float* sWf3 = sWf + 6144;
    const float* sWf4 = sWf + 8192;
    const float* sWf5 = sWf + 9216;

    const int lane = tid & 63;
    const int wid  = tid >> 6;
    const bool lo  = (lane < 32);
    const int  w   = lane & 31;
    const int  iv  = lane >> 5;      // 0 or 1
    float* st = sSt[wid];

    for (int n = blockIdx.x * 8 + wid; n < N; n += gridDim.x * 8) {
        const int beg = rowptr[n];
        const int end = rowptr[n + 1];

        float r0 = 0.f, r1 = 0.f, r2 = 0.f, r3 = 0.f;
        float r4 = 0.f, r5 = 0.f, r6 = 0.f, r7 = 0.f;

#define EDGE_ACC(SH4, XS, VA, VB, VC) do { \
            const float e0 = (SH4).x, e1x = (SH4).y, e1y = (SH4).z, e1z = (SH4).w; \
            r0 += e0  * (XS); \
            r1 += e1x * (XS); \
            r2 += e1y * (XS); \
            r3 += e1z * (XS); \
            r4 += lo ? ((VA) * e1x + (VB) * e1y + (VC) * e1z) : (e0 * (VA)); \
            r5 += e0 * (lo ? (VB) : (VC)); \
            r6 += lo ? ((VB) * e1z - (VC) * e1y) : ((VC) * e1x - (VA) * e1z); \
            r7 += lo ? ((VA) * e1y - (VB) * e1x) : 0.f; \
        } while (0)

        int idx = beg;
        for (; idx + 2 <= end; idx += 2) {
            const int ea = eids[idx], eb = eids[idx + 1];
            const int sa = src[ea],  sb = src[eb];
            const float4 shA = ((const float4*)sh)[ea];
            const float4 shB = ((const float4*)sh)[eb];
            const float* xra = x + (size_t)sa * DFEAT;
            const float* xrb = x + (size_t)sb * DFEAT;
            const float xsA = xra[lane];
            const float vaA = xra[64 + 3 * w], vbA = xra[65 + 3 * w], vcA = xra[66 + 3 * w];
            const float xsB = xrb[lane];
            const float vaB = xrb[64 + 3 * w], vbB = xrb[65 + 3 * w], vcB = xrb[66 + 3 * w];
            EDGE_ACC(shA, xsA, vaA, vbA, vcA);
            EDGE_ACC(shB, xsB, vaB, vbB, vcB);
        }
        if (idx < end) {
            const int ea = eids[idx];
            const int sa = src[ea];
            const float4 shA = ((const float4*)sh)[ea];
            const float* xra = x + (size_t)sa * DFEAT;
            const float xsA = xra[lane];
            const float vaA = xra[64 + 3 * w], vbA = xra[65 + 3 * w], vcA = xra[66 + 3 * w];
            EDGE_ACC(shA, xsA, vaA, vbA, vcA);
        }
#undef EDGE_ACC

        // reduced state layout:
        // [0..63]=A1, [64..127]=INV3·A3x, [128..191]=INV3·A3y, [192..255]=INV3·A3z,
        // [256..287]=INV3·A2, [288..319]=INV3·A4x, [320..351]=INV3·A4y, [352..383]=INV3·A4z,
        // [384..415]=INV6·A5x, [416..447]=INV6·A5y, [448..479]=INV6·A5z
        st[lane]       = r0;
        st[64 + lane]  = kINV3 * r1;
        st[128 + lane] = kINV3 * r2;
        st[192 + lane] = kINV3 * r3;
        st[256 + lane] = kINV3 * r4;
        st[320 + lane] = kINV3 * r5;
        st[384 + lane] = kINV6 * r6;
        if (lo) st[448 + lane] = kINV6 * r7;
        WAVE_SYNC();

        const size_t o = (size_t)n * DFEAT;
        // ---- hs[lane]
        {
            float a = 0.f;
            #pragma unroll 8
            for (int k = 0; k < 64; ++k) a += st[k] * sWf1[k * 64 + lane];
            #pragma unroll 8
            for (int k = 0; k < 32; ++k) a += st[256 + k] * sWf2[k * 64 + lane];
            out[o + lane] = x[o + lane] + fmaxf(kLS * kC0 * a, 0.f);
        }
        // ---- hv[w, iv] for iv=0,1 (full wave)
        {
            float b = 0.f;
            #pragma unroll 8
            for (int k = 0; k < 64; ++k) b += st[64 + 64 * iv + k] * sWf3[k * 32 + w];
            #pragma unroll 8
            for (int k = 0; k < 32; ++k) b += st[288 + 32 * iv + k] * sWf4[k * 32 + w];
            #pragma unroll 8
            for (int k = 0; k < 32; ++k) b += st[384 + 32 * iv + k] * sWf5[k * 32 + w];
            out[o + 64 + 3 * w + iv] = x[o + 64 + 3 * w + iv] + fmaxf(kLV * kC1 * b, 0.f);
        }
        // ---- hv[lane, 2] (lanes < 32)
        if (lo) {
            float c = 0.f;
            #pragma unroll 8
            for (int k = 0; k < 64; ++k) c += st[192 + k] * sWf3[k * 32 + lane];
            #pragma unroll 8
            for (int k = 0; k < 32; ++k) c += st[352 + k] * sWf4[k * 32 + lane];
            #pragma unroll 8
            for (int k = 0; k < 32; ++k) c += st[448 + k] * sWf5[k * 32 + lane];
            out[o + 64 + 3 * lane + 2] = x[o + 64 + 3 * lane + 2] + fmaxf(kLV * kC1 * c, 0.f);
        }
        WAVE_SYNC();  // st reads done before next node's writes
    }
}

extern "C" void kernel_launch(void* const* d_in, const int* in_sizes, int n_in,
                              void* d_out, int out_size, void* d_ws, size_t ws_size,
                              hipStream_t stream) {
    const float* x  = (const float*)d_in[0];
    const float* sh = (const float*)d_in[1];
    const float* W1 = (const float*)d_in[2];
    const float* W2 = (const float*)d_in[3];
    const float* W3 = (const float*)d_in[4];
    const float* W4 = (const float*)d_in[5];
    const float* W5 = (const float*)d_in[6];
    const float* Ws = (const float*)d_in[7];
    const float* Wv = (const float*)d_in[8];
    const int*   ei = (const int*)d_in[9];

    const int E = in_sizes[9] / 2;
    const int N = in_sizes[0] / DFEAT;
    const int* src = ei;
    const int* dst = ei + E;
    const int nb = (N + 1023) / 1024;

    int* deg    = (int*)d_ws;            // N
    int* cursor = deg + N;               // N
    int* rowptr = cursor + N;            // N+1
    int* bsum   = rowptr + N + 1;        // nb (<=64)
    int* eids   = bsum + 64;             // E
    float* wf   = (float*)(eids + E + ((4 - ((size_t)(N * 2 + N + 1 + 64 + E) & 3)) & 3));

    (void)hipMemsetAsync(deg, 0, (size_t)N * sizeof(int), stream);
    hist_kernel<<<512, 256, 0, stream>>>(dst, deg, E);
    blocksum_kernel<<<nb, 256, 0, stream>>>(deg, bsum, N);
    scanb_kernel<<<1, 64, 0, stream>>>(bsum, nb, rowptr + N);
    scanfinal_kernel<<<nb, 256, 0, stream>>>(deg, bsum, rowptr, cursor, N);
    scatter_kernel<<<512, 256, 0, stream>>>(dst, cursor, eids, E);
    fuse_kernel<<<8, 256, 0, stream>>>(W1, W2, W3, W4, W5, Ws, Wv, wf);
    node_fused_kernel<<<1024, 512, 0, stream>>>(x, sh, src, eids, rowptr, wf,
                                                (float*)d_out, N);
}

// Round 10
// 389.020 us; speedup vs baseline: 2.0942x; 1.0142x over previous
//
#include <hip/hip_runtime.h>

#define DFEAT 160

__device__ __constant__ float kINV3 = 0.57735026918962576451f;  // 1/sqrt(3)
__device__ __constant__ float kINV6 = 0.40824829046386301637f;  // 1/sqrt(6)
__device__ __constant__ float kC0   = 0.10206207261596575f;     // 1/sqrt(96)
__device__ __constant__ float kC1   = 0.15309310892394863f;     // sqrt(3/128)
__device__ __constant__ float kLS   = 0.125f;                   // 1/sqrt(64)
__device__ __constant__ float kLV   = 0.17677669529663687f;     // 1/sqrt(32)

#define WAVE_SYNC() do { \
    asm volatile("s_waitcnt lgkmcnt(0)" ::: "memory"); \
    __builtin_amdgcn_sched_barrier(0); \
} while (0)

// ---------- CSR build ----------
__global__ void hist_kernel(const int* __restrict__ dst, int* __restrict__ deg, int E) {
    for (int e = blockIdx.x * blockDim.x + threadIdx.x; e < E; e += gridDim.x * blockDim.x)
        atomicAdd(&deg[dst[e]], 1);
}

__global__ __launch_bounds__(256) void blocksum_kernel(const int* __restrict__ deg,
                                                       int* __restrict__ bsum, int N) {
    __shared__ int red[256];
    const int b = blockIdx.x, t = threadIdx.x;
    const int base = b * 1024;
    int s = 0;
    for (int i = t; i < 1024; i += 256) {
        const int idx = base + i;
        if (idx < N) s += deg[idx];
    }
    red[t] = s;
    __syncthreads();
    for (int off = 128; off > 0; off >>= 1) {
        if (t < off) red[t] += red[t + off];
        __syncthreads();
    }
    if (t == 0) bsum[b] = red[0];
}

__global__ void scanb_kernel(int* __restrict__ bsum, int nb, int* __restrict__ rowptrN) {
    if (threadIdx.x == 0 && blockIdx.x == 0) {
        int run = 0;
        for (int i = 0; i < nb; ++i) { const int v = bsum[i]; bsum[i] = run; run += v; }
        *rowptrN = run;  // == E
    }
}

__global__ __launch_bounds__(256) void scanfinal_kernel(const int* __restrict__ deg,
                                                        const int* __restrict__ bsum,
                                                        int* __restrict__ rowptr,
                                                        int* __restrict__ cursor, int N) {
    __shared__ int ts[256];
    const int b = blockIdx.x, t = threadIdx.x;
    const int i0 = b * 1024 + t * 4;
    const int d0 = (i0 + 0 < N) ? deg[i0 + 0] : 0;
    const int d1 = (i0 + 1 < N) ? deg[i0 + 1] : 0;
    const int d2 = (i0 + 2 < N) ? deg[i0 + 2] : 0;
    const int d3 = (i0 + 3 < N) ? deg[i0 + 3] : 0;
    ts[t] = d0 + d1 + d2 + d3;
    __syncthreads();
    for (int off = 1; off < 256; off <<= 1) {
        const int v = (t >= off) ? ts[t - off] : 0;
        __syncthreads();
        ts[t] += v;
        __syncthreads();
    }
    int ex = bsum[b] + ((t == 0) ? 0 : ts[t - 1]);
    if (i0 + 0 < N) { rowptr[i0 + 0] = ex; cursor[i0 + 0] = ex; ex += d0; }
    if (i0 + 1 < N) { rowptr[i0 + 1] = ex; cursor[i0 + 1] = ex; ex += d1; }
    if (i0 + 2 < N) { rowptr[i0 + 2] = ex; cursor[i0 + 2] = ex; ex += d2; }
    if (i0 + 3 < N) { rowptr[i0 + 3] = ex; cursor[i0 + 3] = ex; ex += d3; }
}

__global__ void scatter_kernel(const int* __restrict__ dst, int* __restrict__ cursor,
                               int* __restrict__ eids, int E) {
    for (int e = blockIdx.x * blockDim.x + threadIdx.x; e < E; e += gridDim.x * blockDim.x) {
        const int pos = atomicAdd(&cursor[dst[e]], 1);
        eids[pos] = e;
    }
}

// ---------- weight fusion: Wf1=W1@Ws, Wf2=W2@Ws, Wf3=W3@Wv, Wf4=W4@Wv, Wf5=W5@Wv
// wf layout (floats): Wf1[64][64]@0, Wf2[32][64]@4096, Wf3[64][32]@6144,
//                     Wf4[32][32]@8192, Wf5[32][32]@9216  (10240 total)
__global__ __launch_bounds__(256) void fuse_kernel(
    const float* __restrict__ W1, const float* __restrict__ W2,
    const float* __restrict__ W3, const float* __restrict__ W4,
    const float* __restrict__ W5, const float* __restrict__ Ws,
    const float* __restrict__ Wv, float* __restrict__ wf)
{
    __shared__ float sWs[4096];
    __shared__ float sWv[1024];
    const int t = threadIdx.x;
    for (int i = t; i < 4096; i += 256) sWs[i] = Ws[i];
    for (int i = t; i < 1024; i += 256) sWv[i] = Wv[i];
    __syncthreads();
    for (int o = blockIdx.x * 256 + t; o < 10240; o += gridDim.x * 256) {
        float acc = 0.f;
        if (o < 4096) {
            const int k = o >> 6, j = o & 63;
            for (int m = 0; m < 64; ++m) acc += W1[k * 64 + m] * sWs[m * 64 + j];
        } else if (o < 6144) {
            const int i = o - 4096; const int k = i >> 6, j = i & 63;
            for (int m = 0; m < 64; ++m) acc += W2[k * 64 + m] * sWs[m * 64 + j];
        } else if (o < 8192) {
            const int i = o - 6144; const int k = i >> 5, j = i & 31;
            for (int m = 0; m < 32; ++m) acc += W3[k * 32 + m] * sWv[m * 32 + j];
        } else if (o < 9216) {
            const int i = o - 8192; const int k = i >> 5, j = i & 31;
            for (int m = 0; m < 32; ++m) acc += W4[k * 32 + m] * sWv[m * 32 + j];
        } else {
            const int i = o - 9216; const int k = i >> 5, j = i & 31;
            for (int m = 0; m < 32; ++m) acc += W5[k * 32 + m] * sWv[m * 32 + j];
        }
        wf[o] = acc;
    }
}

// ---------- fused aggregation + composed node transform ----------
// One wave per node, 8 waves/block. Weights read directly from global (40 KB,
// L1/L2-resident: every wave reads the same lines). LDS = per-wave state only
// (15 KB) -> 4 blocks/CU at VGPR<=64 -> 32 waves/CU for gather-latency hiding.
__global__ __launch_bounds__(512, 8) void node_fused_kernel(
    const float* __restrict__ x, const float* __restrict__ sh,
    const int* __restrict__ src, const int* __restrict__ eids,
    const int* __restrict__ rowptr, const float* __restrict__ wf,
    float* __restrict__ out, int N)
{
    __shared__ float sSt[8][480];

    const float* wf1 = wf;
    const float* wf2 = wf + 4096;
    const float* wf3 = wf + 6144;
    const float* wf4 = wf + 8192;
    const float* wf5 = wf + 9216;

    const int tid  = threadIdx.x;
    const int lane = tid & 63;
    const int wid  = tid >> 6;
    const bool lo  = (lane < 32);
    const int  w   = lane & 31;
    const int  iv  = lane >> 5;      // 0 or 1
    float* st = sSt[wid];

    for (int n = blockIdx.x * 8 + wid; n < N; n += gridDim.x * 8) {
        const int beg = rowptr[n];
        const int end = rowptr[n + 1];

        float r0 = 0.f, r1 = 0.f, r2 = 0.f, r3 = 0.f;
        float r4 = 0.f, r5 = 0.f, r6 = 0.f, r7 = 0.f;

#define EDGE_ACC(SH4, XS, VA, VB, VC) do { \
            const float e0 = (SH4).x, e1x = (SH4).y, e1y = (SH4).z, e1z = (SH4).w; \
            r0 += e0  * (XS); \
            r1 += e1x * (XS); \
            r2 += e1y * (XS); \
            r3 += e1z * (XS); \
            r4 += lo ? ((VA) * e1x + (VB) * e1y + (VC) * e1z) : (e0 * (VA)); \
            r5 += e0 * (lo ? (VB) : (VC)); \
            r6 += lo ? ((VB) * e1z - (VC) * e1y) : ((VC) * e1x - (VA) * e1z); \
            r7 += lo ? ((VA) * e1y - (VB) * e1x) : 0.f; \
        } while (0)

        int idx = beg;
        for (; idx + 2 <= end; idx += 2) {
            const int ea = eids[idx], eb = eids[idx + 1];
            const int sa = src[ea],  sb = src[eb];
            const float4 shA = ((const float4*)sh)[ea];
            const float4 shB = ((const float4*)sh)[eb];
            const float* xra = x + (size_t)sa * DFEAT;
            const float* xrb = x + (size_t)sb * DFEAT;
            const float xsA = xra[lane];
            const float vaA = xra[64 + 3 * w], vbA = xra[65 + 3 * w], vcA = xra[66 + 3 * w];
            const float xsB = xrb[lane];
            const float vaB = xrb[64 + 3 * w], vbB = xrb[65 + 3 * w], vcB = xrb[66 + 3 * w];
            EDGE_ACC(shA, xsA, vaA, vbA, vcA);
            EDGE_ACC(shB, xsB, vaB, vbB, vcB);
        }
        if (idx < end) {
            const int ea = eids[idx];
            const int sa = src[ea];
            const float4 shA = ((const float4*)sh)[ea];
            const float* xra = x + (size_t)sa * DFEAT;
            const float xsA = xra[lane];
            const float vaA = xra[64 + 3 * w], vbA = xra[65 + 3 * w], vcA = xra[66 + 3 * w];
            EDGE_ACC(shA, xsA, vaA, vbA, vcA);
        }
#undef EDGE_ACC

        // reduced state layout:
        // [0..63]=A1, [64..127]=INV3·A3x, [128..191]=INV3·A3y, [192..255]=INV3·A3z,
        // [256..287]=INV3·A2, [288..319]=INV3·A4x, [320..351]=INV3·A4y, [352..383]=INV3·A4z,
        // [384..415]=INV6·A5x, [416..447]=INV6·A5y, [448..479]=INV6·A5z
        st[lane]       = r0;
        st[64 + lane]  = kINV3 * r1;
        st[128 + lane] = kINV3 * r2;
        st[192 + lane] = kINV3 * r3;
        st[256 + lane] = kINV3 * r4;
        st[320 + lane] = kINV3 * r5;
        st[384 + lane] = kINV6 * r6;
        if (lo) st[448 + lane] = kINV6 * r7;
        WAVE_SYNC();

        const size_t o = (size_t)n * DFEAT;
        // ---- hs[lane]
        {
            float a = 0.f;
            #pragma unroll 8
            for (int k = 0; k < 64; ++k) a += st[k] * wf1[k * 64 + lane];
            #pragma unroll 8
            for (int k = 0; k < 32; ++k) a += st[256 + k] * wf2[k * 64 + lane];
            out[o + lane] = x[o + lane] + fmaxf(kLS * kC0 * a, 0.f);
        }
        // ---- hv[w, iv] for iv=0,1 (full wave)
        {
            float b = 0.f;
            #pragma unroll 8
            for (int k = 0; k < 64; ++k) b += st[64 + 64 * iv + k] * wf3[k * 32 + w];
            #pragma unroll 8
            for (int k = 0; k < 32; ++k) b += st[288 + 32 * iv + k] * wf4[k * 32 + w];
            #pragma unroll 8
            for (int k = 0; k < 32; ++k) b += st[384 + 32 * iv + k] * wf5[k * 32 + w];
            out[o + 64 + 3 * w + iv] = x[o + 64 + 3 * w + iv] + fmaxf(kLV * kC1 * b, 0.f);
        }
        // ---- hv[lane, 2] (lanes < 32)
        if (lo) {
            float c = 0.f;
            #pragma unroll 8
            for (int k = 0; k < 64; ++k) c += st[192 + k] * wf3[k * 32 + lane];
            #pragma unroll 8
            for (int k = 0; k < 32; ++k) c += st[352 + k] * wf4[k * 32 + lane];
            #pragma unroll 8
            for (int k = 0; k < 32; ++k) c += st[448 + k] * wf5[k * 32 + lane];
            out[o + 64 + 3 * lane + 2] = x[o + 64 + 3 * lane + 2] + fmaxf(kLV * kC1 * c, 0.f);
        }
        WAVE_SYNC();  // st reads done before next node's writes
    }
}

extern "C" void kernel_launch(void* const* d_in, const int* in_sizes, int n_in,
                              void* d_out, int out_size, void* d_ws, size_t ws_size,
                              hipStream_t stream) {
    const float* x  = (const float*)d_in[0];
    const float* sh = (const float*)d_in[1];
    const float* W1 = (const float*)d_in[2];
    const float* W2 = (const float*)d_in[3];
    const float* W3 = (const float*)d_in[4];
    const float* W4 = (const float*)d_in[5];
    const float* W5 = (const float*)d_in[6];
    const float* Ws = (const float*)d_in[7];
    const float* Wv = (const float*)d_in[8];
    const int*   ei = (const int*)d_in[9];

    const int E = in_sizes[9] / 2;
    const int N = in_sizes[0] / DFEAT;
    const int* src = ei;
    const int* dst = ei + E;
    const int nb = (N + 1023) / 1024;

    int* deg    = (int*)d_ws;            // N
    int* cursor = deg + N;               // N
    int* rowptr = cursor + N;            // N+1
    int* bsum   = rowptr + N + 1;        // nb (<=64)
    int* eids   = bsum + 64;             // E
    float* wf   = (float*)(eids + E + ((4 - ((size_t)(N * 2 + N + 1 + 64 + E) & 3)) & 3));

    (void)hipMemsetAsync(deg, 0, (size_t)N * sizeof(int), stream);
    hist_kernel<<<512, 256, 0, stream>>>(dst, deg, E);
    blocksum_kernel<<<nb, 256, 0, stream>>>(deg, bsum, N);
    scanb_kernel<<<1, 64, 0, stream>>>(bsum, nb, rowptr + N);
    scanfinal_kernel<<<nb, 256, 0, stream>>>(deg, bsum, rowptr, cursor, N);
    scatter_kernel<<<512, 256, 0, stream>>>(dst, cursor, eids, E);
    fuse_kernel<<<8, 256, 0, stream>>>(W1, W2, W3, W4, W5, Ws, Wv, wf);
    node_fused_kernel<<<1024, 512, 0, stream>>>(x, sh, src, eids, rowptr, wf,
                                                (float*)d_out, N);
}

// Round 11
// 295.482 us; speedup vs baseline: 2.7572x; 1.3166x over previous
//
#include <hip/hip_runtime.h>

#define DFEAT 160

typedef float  f4v __attribute__((ext_vector_type(4)));
typedef short  s8v __attribute__((ext_vector_type(8)));

__device__ __constant__ float kINV3 = 0.57735026918962576451f;  // 1/sqrt(3)
__device__ __constant__ float kINV6 = 0.40824829046386301637f;  // 1/sqrt(6)
__device__ __constant__ float kC0   = 0.10206207261596575f;     // 1/sqrt(96)
__device__ __constant__ float kC1   = 0.15309310892394863f;     // sqrt(3/128)
__device__ __constant__ float kLS   = 0.125f;                   // 1/sqrt(64)
__device__ __constant__ float kLV   = 0.17677669529663687f;     // 1/sqrt(32)

#define WAVE_SYNC() do { \
    asm volatile("s_waitcnt lgkmcnt(0)" ::: "memory"); \
    __builtin_amdgcn_sched_barrier(0); \
} while (0)

#define MFMA(a, b, c) __builtin_amdgcn_mfma_f32_16x16x32_bf16((a), (b), (c), 0, 0, 0)

__device__ __forceinline__ unsigned f2bf(float f) {
    const unsigned u = __builtin_bit_cast(unsigned, f);
    const unsigned r = 0x7fffu + ((u >> 16) & 1u);
    return (u + r) >> 16;
}

// ---------- CSR build (padded segments: deg rounded up to x4) ----------
__global__ void hist_kernel(const int* __restrict__ dst, int* __restrict__ deg, int E) {
    for (int e = blockIdx.x * blockDim.x + threadIdx.x; e < E; e += gridDim.x * blockDim.x)
        atomicAdd(&deg[dst[e]], 1);
}

__global__ __launch_bounds__(256) void blocksum_kernel(const int* __restrict__ deg,
                                                       int* __restrict__ bsum, int N) {
    __shared__ int red[256];
    const int b = blockIdx.x, t = threadIdx.x;
    const int base = b * 1024;
    int s = 0;
    for (int i = t; i < 1024; i += 256) {
        const int idx = base + i;
        if (idx < N) s += (deg[idx] + 3) & ~3;
    }
    red[t] = s;
    __syncthreads();
    for (int off = 128; off > 0; off >>= 1) {
        if (t < off) red[t] += red[t + off];
        __syncthreads();
    }
    if (t == 0) bsum[b] = red[0];
}

__global__ void scanb_kernel(int* __restrict__ bsum, int nb, int* __restrict__ rowptrN) {
    if (threadIdx.x == 0 && blockIdx.x == 0) {
        int run = 0;
        for (int i = 0; i < nb; ++i) { const int v = bsum[i]; bsum[i] = run; run += v; }
        *rowptrN = run;
    }
}

__global__ __launch_bounds__(256) void scanfinal_kernel(const int* __restrict__ deg,
                                                        const int* __restrict__ bsum,
                                                        int* __restrict__ rowptr,
                                                        int* __restrict__ cursor, int N) {
    __shared__ int ts[256];
    const int b = blockIdx.x, t = threadIdx.x;
    const int i0 = b * 1024 + t * 4;
    const int d0 = (i0 + 0 < N) ? ((deg[i0 + 0] + 3) & ~3) : 0;
    const int d1 = (i0 + 1 < N) ? ((deg[i0 + 1] + 3) & ~3) : 0;
    const int d2 = (i0 + 2 < N) ? ((deg[i0 + 2] + 3) & ~3) : 0;
    const int d3 = (i0 + 3 < N) ? ((deg[i0 + 3] + 3) & ~3) : 0;
    ts[t] = d0 + d1 + d2 + d3;
    __syncthreads();
    for (int off = 1; off < 256; off <<= 1) {
        const int v = (t >= off) ? ts[t - off] : 0;
        __syncthreads();
        ts[t] += v;
        __syncthreads();
    }
    int ex = bsum[b] + ((t == 0) ? 0 : ts[t - 1]);
    if (i0 + 0 < N) { rowptr[i0 + 0] = ex; cursor[i0 + 0] = ex; ex += d0; }
    if (i0 + 1 < N) { rowptr[i0 + 1] = ex; cursor[i0 + 1] = ex; ex += d1; }
    if (i0 + 2 < N) { rowptr[i0 + 2] = ex; cursor[i0 + 2] = ex; ex += d2; }
    if (i0 + 3 < N) { rowptr[i0 + 3] = ex; cursor[i0 + 3] = ex; ex += d3; }
}

// scatter into sorted streams (src + sh); filler tail slots stay memset-0
__global__ void scatter_kernel(const int* __restrict__ src, const int* __restrict__ dst,
                               const float4* __restrict__ sh, int* __restrict__ cursor,
                               int* __restrict__ src_sorted, float4* __restrict__ sh_sorted,
                               int E) {
    for (int e = blockIdx.x * blockDim.x + threadIdx.x; e < E; e += gridDim.x * blockDim.x) {
        const int pos = atomicAdd(&cursor[dst[e]], 1);
        src_sorted[pos] = src[e];
        sh_sorted[pos] = sh[e];
    }
}

// ---------- weight composition: Wf1=W1@Ws, Wf2=W2@Ws, Wf3..5=W3..5@Wv ----------
// wf (fp32): Wf1[64][64]@0, Wf2[32][64]@4096, Wf3[64][32]@6144, Wf4[32][32]@8192, Wf5[32][32]@9216
__global__ __launch_bounds__(256) void fuse_kernel(
    const float* __restrict__ W1, const float* __restrict__ W2,
    const float* __restrict__ W3, const float* __restrict__ W4,
    const float* __restrict__ W5, const float* __restrict__ Ws,
    const float* __restrict__ Wv, float* __restrict__ wf)
{
    __shared__ float sWs[4096];
    __shared__ float sWv[1024];
    const int t = threadIdx.x;
    for (int i = t; i < 4096; i += 256) sWs[i] = Ws[i];
    for (int i = t; i < 1024; i += 256) sWv[i] = Wv[i];
    __syncthreads();
    for (int o = blockIdx.x * 256 + t; o < 10240; o += gridDim.x * 256) {
        float acc = 0.f;
        if (o < 4096) {
            const int k = o >> 6, j = o & 63;
            for (int m = 0; m < 64; ++m) acc += W1[k * 64 + m] * sWs[m * 64 + j];
        } else if (o < 6144) {
            const int i = o - 4096; const int k = i >> 6, j = i & 63;
            for (int m = 0; m < 64; ++m) acc += W2[k * 64 + m] * sWs[m * 64 + j];
        } else if (o < 8192) {
            const int i = o - 6144; const int k = i >> 5, j = i & 31;
            for (int m = 0; m < 32; ++m) acc += W3[k * 32 + m] * sWv[m * 32 + j];
        } else if (o < 9216) {
            const int i = o - 8192; const int k = i >> 5, j = i & 31;
            for (int m = 0; m < 32; ++m) acc += W4[k * 32 + m] * sWv[m * 32 + j];
        } else {
            const int i = o - 9216; const int k = i >> 5, j = i & 31;
            for (int m = 0; m < 32; ++m) acc += W5[k * 32 + m] * sWv[m * 32 + j];
        }
        wf[o] = acc;
    }
}

// pack wtB[160][480] bf16: row f = output feature, col k = reduced-state index.
// state layout: [0..63]=A1, [64+64i..127+64i]=INV3*A3_i, [256..287]=INV3*A2,
//               [288+32i]=INV3*A4_i, [384+32i]=INV6*A5_i
__global__ __launch_bounds__(256) void pack_kernel(const float* __restrict__ wf,
                                                   unsigned short* __restrict__ wtB)
{
    const int o = blockIdx.x * 256 + threadIdx.x;
    if (o >= 160 * 480) return;
    const int f = o / 480, k = o % 480;
    float v = 0.f;
    if (f < 64) {
        if (k < 64)                  v = kLS * kC0 * wf[k * 64 + f];                     // Wf1
        else if (k >= 256 && k < 288) v = kLS * kC0 * wf[4096 + (k - 256) * 64 + f];     // Wf2
    } else {
        const int w = (f - 64) / 3, i = (f - 64) % 3;
        if (k >= 64 + 64 * i && k < 128 + 64 * i)
            v = kLV * kC1 * wf[6144 + (k - 64 - 64 * i) * 32 + w];                       // Wf3
        else if (k >= 288 + 32 * i && k < 320 + 32 * i)
            v = kLV * kC1 * wf[8192 + (k - 288 - 32 * i) * 32 + w];                      // Wf4
        else if (k >= 384 + 32 * i && k < 416 + 32 * i)
            v = kLV * kC1 * wf[9216 + (k - 384 - 32 * i) * 32 + w];                      // Wf5
    }
    wtB[o] = (unsigned short)f2bf(v);
}

// ---------- aggregation: wave per node, unroll-4 over padded segment ----------
__global__ __launch_bounds__(256, 4) void agg_kernel(
    const float* __restrict__ x, const float4* __restrict__ shs,
    const int* __restrict__ srcs, const int* __restrict__ rowptr,
    unsigned short* __restrict__ st_all, int N)
{
    const int tid  = threadIdx.x;
    const int lane = tid & 63;
    const int wid  = tid >> 6;
    const bool lo  = (lane < 32);
    const int  w   = lane & 31;

    for (int n = blockIdx.x * 4 + wid; n < N; n += gridDim.x * 4) {
        const int beg = rowptr[n];
        const int end = rowptr[n + 1];

        float r0 = 0.f, r1 = 0.f, r2 = 0.f, r3 = 0.f;
        float r4 = 0.f, r5 = 0.f, r6 = 0.f, r7 = 0.f;

#define EDGE_ACC(SH4, XS, VA, VB, VC) do { \
            const float e0 = (SH4).x, e1x = (SH4).y, e1y = (SH4).z, e1z = (SH4).w; \
            r0 += e0  * (XS); \
            r1 += e1x * (XS); \
            r2 += e1y * (XS); \
            r3 += e1z * (XS); \
            r4 += lo ? ((VA) * e1x + (VB) * e1y + (VC) * e1z) : (e0 * (VA)); \
            r5 += e0 * (lo ? (VB) : (VC)); \
            r6 += lo ? ((VB) * e1z - (VC) * e1y) : ((VC) * e1x - (VA) * e1z); \
            r7 += lo ? ((VA) * e1y - (VB) * e1x) : 0.f; \
        } while (0)

        for (int idx = beg; idx < end; idx += 4) {
            const int4 s4 = *(const int4*)(srcs + idx);
            const float4 shA = shs[idx + 0];
            const float4 shB = shs[idx + 1];
            const float4 shC = shs[idx + 2];
            const float4 shD = shs[idx + 3];
            const float* xa = x + (size_t)s4.x * DFEAT;
            const float* xb = x + (size_t)s4.y * DFEAT;
            const float* xc = x + (size_t)s4.z * DFEAT;
            const float* xd = x + (size_t)s4.w * DFEAT;
            const float xsA = xa[lane];
            const float vaA = xa[64 + 3 * w], vbA = xa[65 + 3 * w], vcA = xa[66 + 3 * w];
            const float xsB = xb[lane];
            const float vaB = xb[64 + 3 * w], vbB = xb[65 + 3 * w], vcB = xb[66 + 3 * w];
            const float xsC = xc[lane];
            const float vaC = xc[64 + 3 * w], vbC = xc[65 + 3 * w], vcC = xc[66 + 3 * w];
            const float xsD = xd[lane];
            const float vaD = xd[64 + 3 * w], vbD = xd[65 + 3 * w], vcD = xd[66 + 3 * w];
            EDGE_ACC(shA, xsA, vaA, vbA, vcA);
            EDGE_ACC(shB, xsB, vaB, vbB, vcB);
            EDGE_ACC(shC, xsC, vaC, vbC, vcC);
            EDGE_ACC(shD, xsD, vaD, vbD, vcD);
        }
#undef EDGE_ACC

        // all 8 sections are lane-contiguous -> coalesced u16 stores
        unsigned short* sr = st_all + (size_t)n * 480;
        sr[lane]       = (unsigned short)f2bf(r0);
        sr[64 + lane]  = (unsigned short)f2bf(kINV3 * r1);
        sr[128 + lane] = (unsigned short)f2bf(kINV3 * r2);
        sr[192 + lane] = (unsigned short)f2bf(kINV3 * r3);
        sr[256 + lane] = (unsigned short)f2bf(kINV3 * r4);
        sr[320 + lane] = (unsigned short)f2bf(kINV3 * r5);
        sr[384 + lane] = (unsigned short)f2bf(kINV6 * r6);
        if (lo) sr[448 + lane] = (unsigned short)f2bf(kINV6 * r7);
    }
}

// ---------- transform: MFMA, 16 nodes x 160 feats per wave ----------
__global__ __launch_bounds__(256, 4) void transform_kernel(
    const float* __restrict__ x, const unsigned short* __restrict__ st_all,
    const unsigned short* __restrict__ wtB, float* __restrict__ out, int N)
{
    __shared__ float sEp[4][16][17];
    const int tid  = threadIdx.x;
    const int lane = tid & 63;
    const int wid  = tid >> 6;
    const int l15  = lane & 15;
    const int pp   = lane >> 4;
    const int ntiles = (N + 15) >> 4;

    for (int tile = blockIdx.x * 4 + wid; tile < ntiles; tile += gridDim.x * 4) {
        const int n0 = tile * 16;
        const int nd = n0 + l15;
        const int ndc = (nd < N) ? nd : (N - 1);

        // A-frags: node row = l15, k-chunk pp*8 within each 32-k block
        s8v a[15];
        #pragma unroll
        for (int kc = 0; kc < 15; ++kc)
            a[kc] = *(const s8v*)(st_all + (size_t)ndc * 480 + kc * 32 + pp * 8);

        for (int t = 0; t < 10; ++t) {
            f4v acc = (f4v){0.f, 0.f, 0.f, 0.f};
            const unsigned short* wrow = wtB + (size_t)(16 * t + l15) * 480 + pp * 8;
            if (t < 4) {  // hs rows use only A1 (kc 0,1) + A2 (kc 8)
                acc = MFMA(a[0], *(const s8v*)(wrow + 0 * 32), acc);
                acc = MFMA(a[1], *(const s8v*)(wrow + 1 * 32), acc);
                acc = MFMA(a[8], *(const s8v*)(wrow + 8 * 32), acc);
            } else {      // hv rows use A3 (kc 2..7) + A4 (9..11) + A5 (12..14)
                #pragma unroll
                for (int kc = 2; kc <= 7; ++kc)
                    acc = MFMA(a[kc], *(const s8v*)(wrow + kc * 32), acc);
                #pragma unroll
                for (int kc = 9; kc <= 14; ++kc)
                    acc = MFMA(a[kc], *(const s8v*)(wrow + kc * 32), acc);
            }
            // D: node = pp*4+j, feat = 16t + l15 -> LDS transpose -> coalesced write
            WAVE_SYNC();  // prior epilogue reads done before overwrite
            #pragma unroll
            for (int j = 0; j < 4; ++j)
                sEp[wid][pp * 4 + j][l15] = acc[j];
            WAVE_SYNC();
            #pragma unroll
            for (int it = 0; it < 4; ++it) {
                const int q  = it * 4 + pp;
                const int nq = n0 + q;
                if (nq < N) {
                    const float h = sEp[wid][q][l15];
                    const size_t off = (size_t)nq * DFEAT + 16 * t + l15;
                    out[off] = x[off] + fmaxf(h, 0.f);
                }
            }
        }
    }
}

extern "C" void kernel_launch(void* const* d_in, const int* in_sizes, int n_in,
                              void* d_out, int out_size, void* d_ws, size_t ws_size,
                              hipStream_t stream) {
    const float* x  = (const float*)d_in[0];
    const float* sh = (const float*)d_in[1];
    const float* W1 = (const float*)d_in[2];
    const float* W2 = (const float*)d_in[3];
    const float* W3 = (const float*)d_in[4];
    const float* W4 = (const float*)d_in[5];
    const float* W5 = (const float*)d_in[6];
    const float* Ws = (const float*)d_in[7];
    const float* Wv = (const float*)d_in[8];
    const int*   ei = (const int*)d_in[9];

    const int E = in_sizes[9] / 2;
    const int N = in_sizes[0] / DFEAT;
    const int* src = ei;
    const int* dst = ei + E;
    const int nb = (N + 1023) / 1024;
    const size_t Ep = (size_t)E + 3 * (size_t)N + 16;  // padded-edge capacity

    // workspace layout (16B-aligned sections first)
    char* p = (char*)d_ws;
    float4* sh_sorted = (float4*)p;                 p += Ep * 16;
    unsigned short* st_all = (unsigned short*)p;    p += (size_t)N * 480 * 2;
    unsigned short* wtB = (unsigned short*)p;       p += 160 * 480 * 2;
    int* src_sorted = (int*)p;                      p += Ep * 4;
    float* wf = (float*)p;                          p += 10240 * 4;
    int* deg = (int*)p;                             p += (size_t)N * 4;
    int* cursor = (int*)p;                          p += (size_t)N * 4;
    int* rowptr = (int*)p;                          p += ((size_t)N + 1) * 4;
    int* bsum = (int*)p;

    (void)hipMemsetAsync(deg, 0, (size_t)N * sizeof(int), stream);
    (void)hipMemsetAsync(src_sorted, 0, Ep * sizeof(int), stream);
    (void)hipMemsetAsync(sh_sorted, 0, Ep * sizeof(float4), stream);

    hist_kernel<<<512, 256, 0, stream>>>(dst, deg, E);
    blocksum_kernel<<<nb, 256, 0, stream>>>(deg, bsum, N);
    scanb_kernel<<<1, 64, 0, stream>>>(bsum, nb, rowptr + N);
    scanfinal_kernel<<<nb, 256, 0, stream>>>(deg, bsum, rowptr, cursor, N);
    scatter_kernel<<<512, 256, 0, stream>>>(src, dst, (const float4*)sh, cursor,
                                            src_sorted, sh_sorted, E);
    fuse_kernel<<<8, 256, 0, stream>>>(W1, W2, W3, W4, W5, Ws, Wv, wf);
    pack_kernel<<<300, 256, 0, stream>>>(wf, wtB);
    agg_kernel<<<2048, 256, 0, stream>>>(x, sh_sorted, src_sorted, rowptr, st_all, N);
    transform_kernel<<<800, 256, 0, stream>>>(x, st_all, wtB, (float*)d_out, N);
}

// Round 12
// 263.032 us; speedup vs baseline: 3.0973x; 1.1234x over previous
//
#include <hip/hip_runtime.h>

#define DFEAT 160

typedef float  f4v __attribute__((ext_vector_type(4)));
typedef short  s8v __attribute__((ext_vector_type(8)));

__device__ __constant__ float kINV3 = 0.57735026918962576451f;  // 1/sqrt(3)
__device__ __constant__ float kINV6 = 0.40824829046386301637f;  // 1/sqrt(6)
__device__ __constant__ float kC0   = 0.10206207261596575f;     // 1/sqrt(96)
__device__ __constant__ float kC1   = 0.15309310892394863f;     // sqrt(3/128)
__device__ __constant__ float kLS   = 0.125f;                   // 1/sqrt(64)
__device__ __constant__ float kLV   = 0.17677669529663687f;     // 1/sqrt(32)

#define WAVE_SYNC() do { \
    asm volatile("s_waitcnt lgkmcnt(0)" ::: "memory"); \
    __builtin_amdgcn_sched_barrier(0); \
} while (0)

#define MFMA(a, b, c) __builtin_amdgcn_mfma_f32_16x16x32_bf16((a), (b), (c), 0, 0, 0)

__device__ __forceinline__ unsigned f2bf(float f) {
    const unsigned u = __builtin_bit_cast(unsigned, f);
    const unsigned r = 0x7fffu + ((u >> 16) & 1u);
    return (u + r) >> 16;
}

// ---------- CSR build (padded segments: deg rounded up to x4) ----------
__global__ void hist_kernel(const int* __restrict__ dst, int* __restrict__ deg, int E) {
    for (int e = blockIdx.x * blockDim.x + threadIdx.x; e < E; e += gridDim.x * blockDim.x)
        atomicAdd(&deg[dst[e]], 1);
}

__global__ __launch_bounds__(256) void blocksum_kernel(const int* __restrict__ deg,
                                                       int* __restrict__ bsum, int N) {
    __shared__ int red[256];
    const int b = blockIdx.x, t = threadIdx.x;
    const int base = b * 1024;
    int s = 0;
    for (int i = t; i < 1024; i += 256) {
        const int idx = base + i;
        if (idx < N) s += (deg[idx] + 3) & ~3;
    }
    red[t] = s;
    __syncthreads();
    for (int off = 128; off > 0; off >>= 1) {
        if (t < off) red[t] += red[t + off];
        __syncthreads();
    }
    if (t == 0) bsum[b] = red[0];
}

__global__ void scanb_kernel(int* __restrict__ bsum, int nb, int* __restrict__ rowptrN) {
    if (threadIdx.x == 0 && blockIdx.x == 0) {
        int run = 0;
        for (int i = 0; i < nb; ++i) { const int v = bsum[i]; bsum[i] = run; run += v; }
        *rowptrN = run;
    }
}

// also writes the <=3 filler slots per node (src=0, sh=0) so no big memsets needed
__global__ __launch_bounds__(256) void scanfinal_kernel(const int* __restrict__ deg,
                                                        const int* __restrict__ bsum,
                                                        int* __restrict__ rowptr,
                                                        int* __restrict__ cursor,
                                                        int* __restrict__ src_sorted,
                                                        float4* __restrict__ sh_sorted,
                                                        int N) {
    __shared__ int ts[256];
    const int b = blockIdx.x, t = threadIdx.x;
    const int i0 = b * 1024 + t * 4;
    int dO[4], dP[4];
    #pragma unroll
    for (int j = 0; j < 4; ++j) {
        dO[j] = (i0 + j < N) ? deg[i0 + j] : 0;
        dP[j] = (dO[j] + 3) & ~3;
    }
    ts[t] = dP[0] + dP[1] + dP[2] + dP[3];
    __syncthreads();
    for (int off = 1; off < 256; off <<= 1) {
        const int v = (t >= off) ? ts[t - off] : 0;
        __syncthreads();
        ts[t] += v;
        __syncthreads();
    }
    int ex = bsum[b] + ((t == 0) ? 0 : ts[t - 1]);
    const float4 z4 = make_float4(0.f, 0.f, 0.f, 0.f);
    #pragma unroll
    for (int j = 0; j < 4; ++j) {
        if (i0 + j < N) {
            rowptr[i0 + j] = ex;
            cursor[i0 + j] = ex;
            for (int f = ex + dO[j]; f < ex + dP[j]; ++f) {
                src_sorted[f] = 0;
                sh_sorted[f] = z4;
            }
            ex += dP[j];
        }
    }
}

// scatter into sorted streams (src + sh)
__global__ void scatter_kernel(const int* __restrict__ src, const int* __restrict__ dst,
                               const float4* __restrict__ sh, int* __restrict__ cursor,
                               int* __restrict__ src_sorted, float4* __restrict__ sh_sorted,
                               int E) {
    for (int e = blockIdx.x * blockDim.x + threadIdx.x; e < E; e += gridDim.x * blockDim.x) {
        const int pos = atomicAdd(&cursor[dst[e]], 1);
        src_sorted[pos] = src[e];
        sh_sorted[pos] = sh[e];
    }
}

// ---------- weight composition: Wf1=W1@Ws, Wf2=W2@Ws, Wf3..5=W3..5@Wv ----------
__global__ __launch_bounds__(256) void fuse_kernel(
    const float* __restrict__ W1, const float* __restrict__ W2,
    const float* __restrict__ W3, const float* __restrict__ W4,
    const float* __restrict__ W5, const float* __restrict__ Ws,
    const float* __restrict__ Wv, float* __restrict__ wf)
{
    __shared__ float sWs[4096];
    __shared__ float sWv[1024];
    const int t = threadIdx.x;
    for (int i = t; i < 4096; i += 256) sWs[i] = Ws[i];
    for (int i = t; i < 1024; i += 256) sWv[i] = Wv[i];
    __syncthreads();
    for (int o = blockIdx.x * 256 + t; o < 10240; o += gridDim.x * 256) {
        float acc = 0.f;
        if (o < 4096) {
            const int k = o >> 6, j = o & 63;
            for (int m = 0; m < 64; ++m) acc += W1[k * 64 + m] * sWs[m * 64 + j];
        } else if (o < 6144) {
            const int i = o - 4096; const int k = i >> 6, j = i & 63;
            for (int m = 0; m < 64; ++m) acc += W2[k * 64 + m] * sWs[m * 64 + j];
        } else if (o < 8192) {
            const int i = o - 6144; const int k = i >> 5, j = i & 31;
            for (int m = 0; m < 32; ++m) acc += W3[k * 32 + m] * sWv[m * 32 + j];
        } else if (o < 9216) {
            const int i = o - 8192; const int k = i >> 5, j = i & 31;
            for (int m = 0; m < 32; ++m) acc += W4[k * 32 + m] * sWv[m * 32 + j];
        } else {
            const int i = o - 9216; const int k = i >> 5, j = i & 31;
            for (int m = 0; m < 32; ++m) acc += W5[k * 32 + m] * sWv[m * 32 + j];
        }
        wf[o] = acc;
    }
}

// pack wtB[160][480] bf16 (B-operand rows = output feature, cols = state index)
__global__ __launch_bounds__(256) void pack_kernel(const float* __restrict__ wf,
                                                   unsigned short* __restrict__ wtB)
{
    const int o = blockIdx.x * 256 + threadIdx.x;
    if (o >= 160 * 480) return;
    const int f = o / 480, k = o % 480;
    float v = 0.f;
    if (f < 64) {
        if (k < 64)                  v = kLS * kC0 * wf[k * 64 + f];                     // Wf1
        else if (k >= 256 && k < 288) v = kLS * kC0 * wf[4096 + (k - 256) * 64 + f];     // Wf2
    } else {
        const int w = (f - 64) / 3, i = (f - 64) % 3;
        if (k >= 64 + 64 * i && k < 128 + 64 * i)
            v = kLV * kC1 * wf[6144 + (k - 64 - 64 * i) * 32 + w];                       // Wf3
        else if (k >= 288 + 32 * i && k < 320 + 32 * i)
            v = kLV * kC1 * wf[8192 + (k - 288 - 32 * i) * 32 + w];                      // Wf4
        else if (k >= 384 + 32 * i && k < 416 + 32 * i)
            v = kLV * kC1 * wf[9216 + (k - 384 - 32 * i) * 32 + w];                      // Wf5
    }
    wtB[o] = (unsigned short)f2bf(v);
}

// ---------- aggregation: wave/node; edge PAIRS, half-wave v-split, no divergence ----------
__global__ __launch_bounds__(256, 4) void agg_kernel(
    const float* __restrict__ x, const float4* __restrict__ shs,
    const int* __restrict__ srcs, const int* __restrict__ rowptr,
    unsigned short* __restrict__ st_all, int N)
{
    const int tid  = threadIdx.x;
    const int lane = tid & 63;
    const int wid  = tid >> 6;
    const bool lo  = (lane < 32);
    const int  w   = lane & 31;

    for (int n = blockIdx.x * 4 + wid; n < N; n += gridDim.x * 4) {
        const int beg = rowptr[n];
        const int end = rowptr[n + 1];

        float r0 = 0.f, r1 = 0.f, r2 = 0.f, r3 = 0.f;
        float a2 = 0.f, a4x = 0.f, a4y = 0.f, a4z = 0.f;
        float a5x = 0.f, a5y = 0.f, a5z = 0.f;

#define PAIR(SA, SB, SHA, SHB) do { \
            const float* xa = x + (size_t)(SA) * DFEAT; \
            const float* xb = x + (size_t)(SB) * DFEAT; \
            const float xsA = xa[lane]; \
            const float xsB = xb[lane]; \
            const float* xh = lo ? xa : xb; \
            const float va = xh[64 + 3 * w]; \
            const float vb = xh[65 + 3 * w]; \
            const float vc = xh[66 + 3 * w]; \
            r0 += (SHA).x * xsA;  r0 += (SHB).x * xsB; \
            r1 += (SHA).y * xsA;  r1 += (SHB).y * xsB; \
            r2 += (SHA).z * xsA;  r2 += (SHB).z * xsB; \
            r3 += (SHA).w * xsA;  r3 += (SHB).w * xsB; \
            const float he0 = lo ? (SHA).x : (SHB).x; \
            const float he1x = lo ? (SHA).y : (SHB).y; \
            const float he1y = lo ? (SHA).z : (SHB).z; \
            const float he1z = lo ? (SHA).w : (SHB).w; \
            a2  += va * he1x + vb * he1y + vc * he1z; \
            a4x += he0 * va;  a4y += he0 * vb;  a4z += he0 * vc; \
            a5x += vb * he1z;  a5x -= vc * he1y; \
            a5y += vc * he1x;  a5y -= va * he1z; \
            a5z += va * he1y;  a5z -= vb * he1x; \
        } while (0)

        for (int idx = beg; idx < end; idx += 4) {
            const int4 s4 = *(const int4*)(srcs + idx);
            const float4 shA = shs[idx + 0];
            const float4 shB = shs[idx + 1];
            const float4 shC = shs[idx + 2];
            const float4 shD = shs[idx + 3];
            PAIR(s4.x, s4.y, shA, shB);
            PAIR(s4.z, s4.w, shC, shD);
        }
#undef PAIR

        // combine half-wave partials (both halves end with totals)
        a2  += __shfl_xor(a2, 32);
        a4x += __shfl_xor(a4x, 32);
        a4y += __shfl_xor(a4y, 32);
        a4z += __shfl_xor(a4z, 32);
        a5x += __shfl_xor(a5x, 32);
        a5y += __shfl_xor(a5y, 32);
        a5z += __shfl_xor(a5z, 32);

        // state layout (same as before): [0..63]=A1, [64/128/192]=INV3*A3x/y/z,
        // [256]=INV3*A2, [288]=INV3*A4x, [320]=INV3*A4y, [352]=INV3*A4z,
        // [384]=INV6*A5x, [416]=INV6*A5y, [448]=INV6*A5z
        unsigned short* sr = st_all + (size_t)n * 480;
        sr[lane]       = (unsigned short)f2bf(r0);
        sr[64 + lane]  = (unsigned short)f2bf(kINV3 * r1);
        sr[128 + lane] = (unsigned short)f2bf(kINV3 * r2);
        sr[192 + lane] = (unsigned short)f2bf(kINV3 * r3);
        sr[256 + lane] = (unsigned short)f2bf(kINV3 * (lo ? a2 : a4x));
        sr[320 + lane] = (unsigned short)f2bf(lo ? (kINV3 * a4y) : (kINV3 * a4z));
        sr[384 + lane] = (unsigned short)f2bf(lo ? (kINV6 * a5x) : (kINV6 * a5y));
        if (lo) sr[448 + lane] = (unsigned short)f2bf(kINV6 * a5z);
    }
}

// ---------- transform: MFMA, 16 nodes x 160 feats per wave ----------
__global__ __launch_bounds__(256, 4) void transform_kernel(
    const float* __restrict__ x, const unsigned short* __restrict__ st_all,
    const unsigned short* __restrict__ wtB, float* __restrict__ out, int N)
{
    __shared__ float sEp[4][16][17];
    const int tid  = threadIdx.x;
    const int lane = tid & 63;
    const int wid  = tid >> 6;
    const int l15  = lane & 15;
    const int pp   = lane >> 4;
    const int ntiles = (N + 15) >> 4;

    for (int tile = blockIdx.x * 4 + wid; tile < ntiles; tile += gridDim.x * 4) {
        const int n0 = tile * 16;
        const int nd = n0 + l15;
        const int ndc = (nd < N) ? nd : (N - 1);

        s8v a[15];
        #pragma unroll
        for (int kc = 0; kc < 15; ++kc)
            a[kc] = *(const s8v*)(st_all + (size_t)ndc * 480 + kc * 32 + pp * 8);

        for (int t = 0; t < 10; ++t) {
            f4v acc = (f4v){0.f, 0.f, 0.f, 0.f};
            const unsigned short* wrow = wtB + (size_t)(16 * t + l15) * 480 + pp * 8;
            if (t < 4) {  // hs rows: A1 (kc 0,1) + A2 (kc 8)
                acc = MFMA(a[0], *(const s8v*)(wrow + 0 * 32), acc);
                acc = MFMA(a[1], *(const s8v*)(wrow + 1 * 32), acc);
                acc = MFMA(a[8], *(const s8v*)(wrow + 8 * 32), acc);
            } else {      // hv rows: A3 (kc 2..7) + A4 (9..11) + A5 (12..14)
                #pragma unroll
                for (int kc = 2; kc <= 7; ++kc)
                    acc = MFMA(a[kc], *(const s8v*)(wrow + kc * 32), acc);
                #pragma unroll
                for (int kc = 9; kc <= 14; ++kc)
                    acc = MFMA(a[kc], *(const s8v*)(wrow + kc * 32), acc);
            }
            WAVE_SYNC();
            #pragma unroll
            for (int j = 0; j < 4; ++j)
                sEp[wid][pp * 4 + j][l15] = acc[j];
            WAVE_SYNC();
            #pragma unroll
            for (int it = 0; it < 4; ++it) {
                const int q  = it * 4 + pp;
                const int nq = n0 + q;
                if (nq < N) {
                    const float h = sEp[wid][q][l15];
                    const size_t off = (size_t)nq * DFEAT + 16 * t + l15;
                    out[off] = x[off] + fmaxf(h, 0.f);
                }
            }
        }
    }
}

extern "C" void kernel_launch(void* const* d_in, const int* in_sizes, int n_in,
                              void* d_out, int out_size, void* d_ws, size_t ws_size,
                              hipStream_t stream) {
    const float* x  = (const float*)d_in[0];
    const float* sh = (const float*)d_in[1];
    const float* W1 = (const float*)d_in[2];
    const float* W2 = (const float*)d_in[3];
    const float* W3 = (const float*)d_in[4];
    const float* W4 = (const float*)d_in[5];
    const float* W5 = (const float*)d_in[6];
    const float* Ws = (const float*)d_in[7];
    const float* Wv = (const float*)d_in[8];
    const int*   ei = (const int*)d_in[9];

    const int E = in_sizes[9] / 2;
    const int N = in_sizes[0] / DFEAT;
    const int* src = ei;
    const int* dst = ei + E;
    const int nb = (N + 1023) / 1024;
    const size_t Ep = (size_t)E + 3 * (size_t)N + 16;  // padded-edge capacity

    char* p = (char*)d_ws;
    float4* sh_sorted = (float4*)p;                 p += Ep * 16;
    unsigned short* st_all = (unsigned short*)p;    p += (size_t)N * 480 * 2;
    unsigned short* wtB = (unsigned short*)p;       p += 160 * 480 * 2;
    int* src_sorted = (int*)p;                      p += Ep * 4;
    float* wf = (float*)p;                          p += 10240 * 4;
    int* deg = (int*)p;                             p += (size_t)N * 4;
    int* cursor = (int*)p;                          p += (size_t)N * 4;
    int* rowptr = (int*)p;                          p += ((size_t)N + 1) * 4;
    int* bsum = (int*)p;

    (void)hipMemsetAsync(deg, 0, (size_t)N * sizeof(int), stream);

    hist_kernel<<<512, 256, 0, stream>>>(dst, deg, E);
    blocksum_kernel<<<nb, 256, 0, stream>>>(deg, bsum, N);
    scanb_kernel<<<1, 64, 0, stream>>>(bsum, nb, rowptr + N);
    scanfinal_kernel<<<nb, 256, 0, stream>>>(deg, bsum, rowptr, cursor,
                                             src_sorted, sh_sorted, N);
    scatter_kernel<<<512, 256, 0, stream>>>(src, dst, (const float4*)sh, cursor,
                                            src_sorted, sh_sorted, E);
    fuse_kernel<<<8, 256, 0, stream>>>(W1, W2, W3, W4, W5, Ws, Wv, wf);
    pack_kernel<<<300, 256, 0, stream>>>(wf, wtB);
    agg_kernel<<<2048, 256, 0, stream>>>(x, sh_sorted, src_sorted, rowptr, st_all, N);
    transform_kernel<<<800, 256, 0, stream>>>(x, st_all, wtB, (float*)d_out, N);
}

// Round 13
// 242.117 us; speedup vs baseline: 3.3649x; 1.0864x over previous
//
#include <hip/hip_runtime.h>

#define DFEAT 160

typedef float  f4v __attribute__((ext_vector_type(4)));
typedef short  s8v __attribute__((ext_vector_type(8)));

__device__ __constant__ float kINV3 = 0.57735026918962576451f;  // 1/sqrt(3)
__device__ __constant__ float kINV6 = 0.40824829046386301637f;  // 1/sqrt(6)
__device__ __constant__ float kC0   = 0.10206207261596575f;     // 1/sqrt(96)
__device__ __constant__ float kC1   = 0.15309310892394863f;     // sqrt(3/128)
__device__ __constant__ float kLS   = 0.125f;                   // 1/sqrt(64)
__device__ __constant__ float kLV   = 0.17677669529663687f;     // 1/sqrt(32)

#define WAVE_SYNC() do { \
    asm volatile("s_waitcnt lgkmcnt(0)" ::: "memory"); \
    __builtin_amdgcn_sched_barrier(0); \
} while (0)

#define MFMA(a, b, c) __builtin_amdgcn_mfma_f32_16x16x32_bf16((a), (b), (c), 0, 0, 0)

__device__ __forceinline__ unsigned f2bf(float f) {
    const unsigned u = __builtin_bit_cast(unsigned, f);
    const unsigned r = 0x7fffu + ((u >> 16) & 1u);
    return (u + r) >> 16;
}

// ---------- CSR build (padded segments: deg rounded up to x4) ----------
__global__ void hist_kernel(const int* __restrict__ dst, int* __restrict__ deg, int E) {
    for (int e = blockIdx.x * blockDim.x + threadIdx.x; e < E; e += gridDim.x * blockDim.x)
        atomicAdd(&deg[dst[e]], 1);
}

__global__ __launch_bounds__(256) void blocksum_kernel(const int* __restrict__ deg,
                                                       int* __restrict__ bsum, int N) {
    __shared__ int red[256];
    const int b = blockIdx.x, t = threadIdx.x;
    const int base = b * 1024;
    int s = 0;
    for (int i = t; i < 1024; i += 256) {
        const int idx = base + i;
        if (idx < N) s += (deg[idx] + 3) & ~3;
    }
    red[t] = s;
    __syncthreads();
    for (int off = 128; off > 0; off >>= 1) {
        if (t < off) red[t] += red[t + off];
        __syncthreads();
    }
    if (t == 0) bsum[b] = red[0];
}

__global__ void scanb_kernel(int* __restrict__ bsum, int nb, int* __restrict__ rowptrN) {
    if (threadIdx.x == 0 && blockIdx.x == 0) {
        int run = 0;
        for (int i = 0; i < nb; ++i) { const int v = bsum[i]; bsum[i] = run; run += v; }
        *rowptrN = run;
    }
}

// also writes the <=3 filler slots per node (src=0, sh=0) so no big memsets needed
__global__ __launch_bounds__(256) void scanfinal_kernel(const int* __restrict__ deg,
                                                        const int* __restrict__ bsum,
                                                        int* __restrict__ rowptr,
                                                        int* __restrict__ cursor,
                                                        int* __restrict__ src_sorted,
                                                        float4* __restrict__ sh_sorted,
                                                        int N) {
    __shared__ int ts[256];
    const int b = blockIdx.x, t = threadIdx.x;
    const int i0 = b * 1024 + t * 4;
    int dO[4], dP[4];
    #pragma unroll
    for (int j = 0; j < 4; ++j) {
        dO[j] = (i0 + j < N) ? deg[i0 + j] : 0;
        dP[j] = (dO[j] + 3) & ~3;
    }
    ts[t] = dP[0] + dP[1] + dP[2] + dP[3];
    __syncthreads();
    for (int off = 1; off < 256; off <<= 1) {
        const int v = (t >= off) ? ts[t - off] : 0;
        __syncthreads();
        ts[t] += v;
        __syncthreads();
    }
    int ex = bsum[b] + ((t == 0) ? 0 : ts[t - 1]);
    const float4 z4 = make_float4(0.f, 0.f, 0.f, 0.f);
    #pragma unroll
    for (int j = 0; j < 4; ++j) {
        if (i0 + j < N) {
            rowptr[i0 + j] = ex;
            cursor[i0 + j] = ex;
            for (int f = ex + dO[j]; f < ex + dP[j]; ++f) {
                src_sorted[f] = 0;
                sh_sorted[f] = z4;
            }
            ex += dP[j];
        }
    }
}

// scatter into sorted streams (src + sh)
__global__ void scatter_kernel(const int* __restrict__ src, const int* __restrict__ dst,
                               const float4* __restrict__ sh, int* __restrict__ cursor,
                               int* __restrict__ src_sorted, float4* __restrict__ sh_sorted,
                               int E) {
    for (int e = blockIdx.x * blockDim.x + threadIdx.x; e < E; e += gridDim.x * blockDim.x) {
        const int pos = atomicAdd(&cursor[dst[e]], 1);
        src_sorted[pos] = src[e];
        sh_sorted[pos] = sh[e];
    }
}

// ---------- pack wtB[160][480] bf16 directly from W1..W5, Ws, Wv ----------
// wtB[f][k]: f = output feature, k = reduced-state index.
// f<64 (scalar): k<64 -> LS*C0*(W1@Ws)[k][f]; 256<=k<288 -> LS*C0*(W2@Ws)[k-256][f]
// f>=64 (vector, f=64+3w+i): 64+64i<=k<128+64i -> LV*C1*(W3@Wv)[k'][w]
//                            288+32i<=k<320+32i -> LV*C1*(W4@Wv)[k'][w]
//                            384+32i<=k<416+32i -> LV*C1*(W5@Wv)[k'][w]
__global__ __launch_bounds__(256) void pack_kernel(
    const float* __restrict__ W1, const float* __restrict__ W2,
    const float* __restrict__ W3, const float* __restrict__ W4,
    const float* __restrict__ W5, const float* __restrict__ Ws,
    const float* __restrict__ Wv, unsigned short* __restrict__ wtB)
{
    const int o = blockIdx.x * 256 + threadIdx.x;
    if (o >= 160 * 480) return;
    const int f = o / 480, k = o % 480;
    float v = 0.f;
    if (f < 64) {
        if (k < 64) {
            float a = 0.f;
            for (int m = 0; m < 64; ++m) a += W1[k * 64 + m] * Ws[m * 64 + f];
            v = kLS * kC0 * a;
        } else if (k >= 256 && k < 288) {
            float a = 0.f;
            for (int m = 0; m < 64; ++m) a += W2[(k - 256) * 64 + m] * Ws[m * 64 + f];
            v = kLS * kC0 * a;
        }
    } else {
        const int w = (f - 64) / 3, i = (f - 64) % 3;
        if (k >= 64 + 64 * i && k < 128 + 64 * i) {
            float a = 0.f;
            const int kk = k - 64 - 64 * i;
            for (int m = 0; m < 32; ++m) a += W3[kk * 32 + m] * Wv[m * 32 + w];
            v = kLV * kC1 * a;
        } else if (k >= 288 + 32 * i && k < 320 + 32 * i) {
            float a = 0.f;
            const int kk = k - 288 - 32 * i;
            for (int m = 0; m < 32; ++m) a += W4[kk * 32 + m] * Wv[m * 32 + w];
            v = kLV * kC1 * a;
        } else if (k >= 384 + 32 * i && k < 416 + 32 * i) {
            float a = 0.f;
            const int kk = k - 384 - 32 * i;
            for (int m = 0; m < 32; ++m) a += W5[kk * 32 + m] * Wv[m * 32 + w];
            v = kLV * kC1 * a;
        }
    }
    wtB[o] = (unsigned short)f2bf(v);
}

// ---------- aggregation: wave/node; edge PAIRS, half-wave v-split ----------
__global__ __launch_bounds__(256, 8) void agg_kernel(
    const float* __restrict__ x, const float4* __restrict__ shs,
    const int* __restrict__ srcs, const int* __restrict__ rowptr,
    unsigned short* __restrict__ st_all, int N)
{
    const int tid  = threadIdx.x;
    const int lane = tid & 63;
    const int wid  = tid >> 6;
    const bool lo  = (lane < 32);
    const int  w   = lane & 31;

    for (int n = blockIdx.x * 4 + wid; n < N; n += gridDim.x * 4) {
        const int beg = rowptr[n];
        const int end = rowptr[n + 1];

        float r0 = 0.f, r1 = 0.f, r2 = 0.f, r3 = 0.f;
        float a2 = 0.f, a4x = 0.f, a4y = 0.f, a4z = 0.f;
        float a5x = 0.f, a5y = 0.f, a5z = 0.f;

#define PAIR(SA, SB, SHA, SHB) do { \
            const float* xa = x + (size_t)(SA) * DFEAT; \
            const float* xb = x + (size_t)(SB) * DFEAT; \
            const float xsA = xa[lane]; \
            const float xsB = xb[lane]; \
            const float* xh = lo ? xa : xb; \
            const float va = xh[64 + 3 * w]; \
            const float vb = xh[65 + 3 * w]; \
            const float vc = xh[66 + 3 * w]; \
            r0 += (SHA).x * xsA;  r0 += (SHB).x * xsB; \
            r1 += (SHA).y * xsA;  r1 += (SHB).y * xsB; \
            r2 += (SHA).z * xsA;  r2 += (SHB).z * xsB; \
            r3 += (SHA).w * xsA;  r3 += (SHB).w * xsB; \
            const float he0 = lo ? (SHA).x : (SHB).x; \
            const float he1x = lo ? (SHA).y : (SHB).y; \
            const float he1y = lo ? (SHA).z : (SHB).z; \
            const float he1z = lo ? (SHA).w : (SHB).w; \
            a2  += va * he1x + vb * he1y + vc * he1z; \
            a4x += he0 * va;  a4y += he0 * vb;  a4z += he0 * vc; \
            a5x += vb * he1z;  a5x -= vc * he1y; \
            a5y += vc * he1x;  a5y -= va * he1z; \
            a5z += va * he1y;  a5z -= vb * he1x; \
        } while (0)

        for (int idx = beg; idx < end; idx += 4) {
            const int4 s4 = *(const int4*)(srcs + idx);
            const float4 shA = shs[idx + 0];
            const float4 shB = shs[idx + 1];
            const float4 shC = shs[idx + 2];
            const float4 shD = shs[idx + 3];
            PAIR(s4.x, s4.y, shA, shB);
            PAIR(s4.z, s4.w, shC, shD);
        }
#undef PAIR

        a2  += __shfl_xor(a2, 32);
        a4x += __shfl_xor(a4x, 32);
        a4y += __shfl_xor(a4y, 32);
        a4z += __shfl_xor(a4z, 32);
        a5x += __shfl_xor(a5x, 32);
        a5y += __shfl_xor(a5y, 32);
        a5z += __shfl_xor(a5z, 32);

        unsigned short* sr = st_all + (size_t)n * 480;
        sr[lane]       = (unsigned short)f2bf(r0);
        sr[64 + lane]  = (unsigned short)f2bf(kINV3 * r1);
        sr[128 + lane] = (unsigned short)f2bf(kINV3 * r2);
        sr[192 + lane] = (unsigned short)f2bf(kINV3 * r3);
        sr[256 + lane] = (unsigned short)f2bf(kINV3 * (lo ? a2 : a4x));
        sr[320 + lane] = (unsigned short)f2bf(lo ? (kINV3 * a4y) : (kINV3 * a4z));
        sr[384 + lane] = (unsigned short)f2bf(lo ? (kINV6 * a5x) : (kINV6 * a5y));
        if (lo) sr[448 + lane] = (unsigned short)f2bf(kINV6 * a5z);
    }
}

// ---------- transform: MFMA, 16 nodes x 160 feats per wave ----------
__global__ __launch_bounds__(256, 4) void transform_kernel(
    const float* __restrict__ x, const unsigned short* __restrict__ st_all,
    const unsigned short* __restrict__ wtB, float* __restrict__ out, int N)
{
    __shared__ float sEp[4][16][17];
    const int tid  = threadIdx.x;
    const int lane = tid & 63;
    const int wid  = tid >> 6;
    const int l15  = lane & 15;
    const int pp   = lane >> 4;
    const int ntiles = (N + 15) >> 4;

    for (int tile = blockIdx.x * 4 + wid; tile < ntiles; tile += gridDim.x * 4) {
        const int n0 = tile * 16;
        const int nd = n0 + l15;
        const int ndc = (nd < N) ? nd : (N - 1);

        s8v a[15];
        #pragma unroll
        for (int kc = 0; kc < 15; ++kc)
            a[kc] = *(const s8v*)(st_all + (size_t)ndc * 480 + kc * 32 + pp * 8);

        for (int t = 0; t < 10; ++t) {
            f4v acc = (f4v){0.f, 0.f, 0.f, 0.f};
            const unsigned short* wrow = wtB + (size_t)(16 * t + l15) * 480 + pp * 8;
            if (t < 4) {  // hs rows: A1 (kc 0,1) + A2 (kc 8)
                acc = MFMA(a[0], *(const s8v*)(wrow + 0 * 32), acc);
                acc = MFMA(a[1], *(const s8v*)(wrow + 1 * 32), acc);
                acc = MFMA(a[8], *(const s8v*)(wrow + 8 * 32), acc);
            } else {      // hv rows: A3 (kc 2..7) + A4 (9..11) + A5 (12..14)
                #pragma unroll
                for (int kc = 2; kc <= 7; ++kc)
                    acc = MFMA(a[kc], *(const s8v*)(wrow + kc * 32), acc);
                #pragma unroll
                for (int kc = 9; kc <= 14; ++kc)
                    acc = MFMA(a[kc], *(const s8v*)(wrow + kc * 32), acc);
            }
            WAVE_SYNC();
            #pragma unroll
            for (int j = 0; j < 4; ++j)
                sEp[wid][pp * 4 + j][l15] = acc[j];
            WAVE_SYNC();
            #pragma unroll
            for (int it = 0; it < 4; ++it) {
                const int q  = it * 4 + pp;
                const int nq = n0 + q;
                if (nq < N) {
                    const float h = sEp[wid][q][l15];
                    const size_t off = (size_t)nq * DFEAT + 16 * t + l15;
                    out[off] = x[off] + fmaxf(h, 0.f);
                }
            }
        }
    }
}

extern "C" void kernel_launch(void* const* d_in, const int* in_sizes, int n_in,
                              void* d_out, int out_size, void* d_ws, size_t ws_size,
                              hipStream_t stream) {
    const float* x  = (const float*)d_in[0];
    const float* sh = (const float*)d_in[1];
    const float* W1 = (const float*)d_in[2];
    const float* W2 = (const float*)d_in[3];
    const float* W3 = (const float*)d_in[4];
    const float* W4 = (const float*)d_in[5];
    const float* W5 = (const float*)d_in[6];
    const float* Ws = (const float*)d_in[7];
    const float* Wv = (const float*)d_in[8];
    const int*   ei = (const int*)d_in[9];

    const int E = in_sizes[9] / 2;
    const int N = in_sizes[0] / DFEAT;
    const int* src = ei;
    const int* dst = ei + E;
    const int nb = (N + 1023) / 1024;
    const size_t Ep = (size_t)E + 3 * (size_t)N + 16;  // padded-edge capacity

    char* p = (char*)d_ws;
    float4* sh_sorted = (float4*)p;                 p += Ep * 16;
    unsigned short* st_all = (unsigned short*)p;    p += (size_t)N * 480 * 2;
    unsigned short* wtB = (unsigned short*)p;       p += 160 * 480 * 2;
    int* src_sorted = (int*)p;                      p += Ep * 4;
    int* deg = (int*)p;                             p += (size_t)N * 4;
    int* cursor = (int*)p;                          p += (size_t)N * 4;
    int* rowptr = (int*)p;                          p += ((size_t)N + 1) * 4;
    int* bsum = (int*)p;

    (void)hipMemsetAsync(deg, 0, (size_t)N * sizeof(int), stream);

    hist_kernel<<<512, 256, 0, stream>>>(dst, deg, E);
    blocksum_kernel<<<nb, 256, 0, stream>>>(deg, bsum, N);
    scanb_kernel<<<1, 64, 0, stream>>>(bsum, nb, rowptr + N);
    scanfinal_kernel<<<nb, 256, 0, stream>>>(deg, bsum, rowptr, cursor,
                                             src_sorted, sh_sorted, N);
    scatter_kernel<<<512, 256, 0, stream>>>(src, dst, (const float4*)sh, cursor,
                                            src_sorted, sh_sorted, E);
    pack_kernel<<<300, 256, 0, stream>>>(W1, W2, W3, W4, W5, Ws, Wv, wtB);
    agg_kernel<<<2048, 256, 0, stream>>>(x, sh_sorted, src_sorted, rowptr, st_all, N);
    transform_kernel<<<800, 256, 0, stream>>>(x, st_all, wtB, (float*)d_out, N);
}